// Round 5
// baseline (5844.962 us; speedup 1.0000x reference)
//
#include <hip/hip_runtime.h>
#include <stdint.h>

#define TSTEPS 512
#define NB 512
#define ND 512
#define NH 512
#define SENT 0xFFFFFFFFFFFFFFFFull

typedef _Float16 half8 __attribute__((ext_vector_type(8)));
typedef float float4v __attribute__((ext_vector_type(4)));
typedef unsigned long long u64;

__device__ __forceinline__ float fast_tanh(float x) {
  // tanh(x) = 1 - 2/(e^{2x}+1); saturates correctly at +/-inf, no NaN.
  float e = __expf(2.0f * x);
  return 1.0f - 2.0f * __builtin_amdgcn_rcpf(e + 1.0f);
}

// Agent-scope (sc1, device coherence point) relaxed ops — proven on HW (R1/R2/R4).
#define AL(p)    __hip_atomic_load((p), __ATOMIC_RELAXED, __HIP_MEMORY_SCOPE_AGENT)
#define AS(p, v) __hip_atomic_store((p), (v), __ATOMIC_RELAXED, __HIP_MEMORY_SCOPE_AGENT)

// LDS-only barrier (no vmcnt drain -> in-flight global loads keep flying).
#define LDSBAR()                                                               \
  do {                                                                         \
    asm volatile("s_waitcnt lgkmcnt(0)" ::: "memory");                         \
    __builtin_amdgcn_s_barrier();                                              \
  } while (0)

// Persistent RNN. Grid = 256 WGs x 256 threads, 1 WG/CU. Group g=bid&31 owns
// batch rows [16g,16g+16); col-WG c=bid>>5 owns cols [64c,64c+64). 32
// independent 8-WG rings. h ring of 4 fp16 buffers (sentinel protocol, R4).
//
// R5 restructure — recurrence path decoupled from LDS/barrier:
//  * h-part is COLUMN-split across waves (wave w: 16 rows x 16 cols, full
//    K=512) with SWAPPED MFMA operands: mfma(A=W_hh frag, B=h frag) puts
//    batch-row in the C-layout lane index and 4 consecutive hidden cols in
//    the 4 acc regs -> each thread publishes ONE contiguous 8B word
//    (unique writer, 8B sentinel granularity preserved), and the consumer
//    B-fragment load h[row][k..k+8] is contiguous 16B. No cross-wave
//    reduction, no barrier, no convoy on the recurrence.
//  * x-projection xp[t+1] = x_{t+1} @ W_ih^T + b is h-independent: computed
//    ONE STEP AHEAD (K-split + LDS reduce + single barrier) entirely in the
//    shadow of the h_t wait. Result xp lives in 4 regs, added before tanh.
//  * Step critical path: validate h_t -> 16 MFMA (4 ILP chains) -> +xp ->
//    tanh -> vmcnt -> one 8B publish. Waves fully independent.
//  * Ring/WAR/ABA arguments identical to R4 (clear slot (t+2)&3 at top of
//    step t; vmcnt(0) before publish orders clear ahead of publish).
__global__ void __launch_bounds__(256, 1)
rnn_persistent(const float* __restrict__ x,     // [T,B,D]
               const float* __restrict__ Wih,   // [H,D]
               const float* __restrict__ Whh,   // [H,H]
               const float* __restrict__ bih,   // [H]
               const float* __restrict__ bhh,   // [H]
               float* __restrict__ out,         // [B,H]
               _Float16* __restrict__ hbuf)     // ws: [4][B][H] fp16 ring
{
  __shared__ __attribute__((aligned(16))) float red[2][4][16][68]; // xp dbuf

  const int bid  = blockIdx.x;
  const int grp  = bid & 31;
  const int cwg  = bid >> 5;              // 0..7
  const int wave = threadIdx.x >> 6;      // 0..3
  const int lane = threadIdx.x & 63;
  const int m    = lane & 15;
  const int quad = lane >> 4;

  const int R     = grp * 16;             // batch-row base
  const int C0    = cwg * 64;             // hidden-col base
  const int kbase = wave * 128;           // xp K slice
  const int myrow = R + m;

  // ---- W_ih fragments (MFMA *A* operand now; lane&15 <-> hidden col,
  //      k = quad*8+j within each K=32 slice). Same gather as before —
  //      A and B fragments have identical per-lane indexing on 16x16x32. ----
  half8 wih_f[4][4];  // [kk][tile], K slice kbase.., cols C0+tile*16..
  #pragma unroll
  for (int tile = 0; tile < 4; ++tile) {
    const float* wr = Wih + (size_t)(C0 + tile * 16 + m) * ND;
    #pragma unroll
    for (int kk = 0; kk < 4; ++kk) {
      const int k0 = kbase + kk * 32 + quad * 8;
      half8 a;
      #pragma unroll
      for (int j = 0; j < 8; ++j) a[j] = (_Float16)wr[k0 + j];
      wih_f[kk][tile] = a;
    }
  }

  // ---- W_hh fragments: FULL K=512 for this wave's 16 cols ----
  half8 whh_f[16];
  {
    const float* wr = Whh + (size_t)(C0 + wave * 16 + m) * NH;
    #pragma unroll
    for (int kk = 0; kk < 16; ++kk) {
      const int k0 = kk * 32 + quad * 8;
      half8 a;
      #pragma unroll
      for (int j = 0; j < 8; ++j) a[j] = (_Float16)wr[k0 + j];
      whh_f[kk] = a;
    }
  }

  // ---- publish coords: thread owns (row R+m, cols pubcol..pubcol+4) ----
  const int pubcol = C0 + wave * 16 + quad * 4;
  float4v bias4;
  #pragma unroll
  for (int j = 0; j < 4; ++j)
    bias4[j] = bih[pubcol + j] + bhh[pubcol + j];

  // ---- prologue: xp[0] (buffer 0), prefetch x[1] ----
  float4v xvA[4][2], xvB[4][2];
  float4v xp_cur;
  {
    const float* xr = x + (size_t)myrow * ND + kbase + quad * 8;
    float4v x0[4][2];
    #pragma unroll
    for (int kk = 0; kk < 4; ++kk) {
      x0[kk][0] = *(const float4v*)(xr + kk * 32);
      x0[kk][1] = *(const float4v*)(xr + kk * 32 + 4);
    }
    float4v xacc[4];
    #pragma unroll
    for (int tile = 0; tile < 4; ++tile) xacc[tile] = (float4v){0.f,0.f,0.f,0.f};
    #pragma unroll
    for (int kk = 0; kk < 4; ++kk) {
      half8 a;
      #pragma unroll
      for (int j = 0; j < 4; ++j) {
        a[j] = (_Float16)x0[kk][0][j];
        a[j + 4] = (_Float16)x0[kk][1][j];
      }
      #pragma unroll
      for (int tile = 0; tile < 4; ++tile)
        xacc[tile] = __builtin_amdgcn_mfma_f32_16x16x32_f16(wih_f[kk][tile], a, xacc[tile], 0, 0, 0);
    }
    #pragma unroll
    for (int tile = 0; tile < 4; ++tile)
      *(float4v*)&red[0][wave][m][tile * 16 + quad * 4] = xacc[tile];
    LDSBAR();
    xp_cur = bias4;
    #pragma unroll
    for (int w = 0; w < 4; ++w) {
      const float4v v = *(const float4v*)&red[0][w][m][wave * 16 + quad * 4];
      xp_cur[0] += v[0]; xp_cur[1] += v[1]; xp_cur[2] += v[2]; xp_cur[3] += v[3];
    }
    const float* xr1 = x + ((size_t)1 * NB + myrow) * ND + kbase + quad * 8;
    #pragma unroll
    for (int kk = 0; kk < 4; ++kk) {
      xvA[kk][0] = *(const float4v*)(xr1 + kk * 32);
      xvA[kk][1] = *(const float4v*)(xr1 + kk * 32 + 4);
    }
  }

#define STEP(T, PAR, XU, XP)                                                   \
  {                                                                            \
    const int t_ = (T);                                                        \
    /* WAR-safe clear of own publish word in slot (t_+2)&3 (proof as R4) */    \
    if (t_ >= 2) {                                                             \
      AS((u64*)(hbuf + (size_t)((t_ + 2) & 3) * NB * NH +                      \
                (size_t)myrow * NH + pubcol), SENT);                           \
    }                                                                          \
    /* issue the 32 h-loads FIRST (oldest in vmcnt FIFO) */                    \
    const u64* hbase = (const u64*)(hbuf + (size_t)(t_ & 3) * NB * NH +        \
                                    (size_t)myrow * NH);                       \
    u64 hw[32];                                                                \
    if (t_ > 0) {                                                              \
      _Pragma("unroll")                                                        \
      for (int i = 0; i < 32; ++i)                                             \
        hw[i] = AL(hbase + (i >> 1) * 8 + quad * 2 + (i & 1));                 \
    }                                                                          \
    /* then x prefetch for t_+2 (newest -> stays in flight at h-wait) */       \
    {                                                                          \
      const int tn_ = (t_ + 2 < TSTEPS) ? (t_ + 2) : (TSTEPS - 1);             \
      const float* xr_ = x + ((size_t)tn_ * NB + myrow) * ND + kbase + quad * 8; \
      _Pragma("unroll")                                                        \
      for (int kk = 0; kk < 4; ++kk) {                                         \
        XP[kk][0] = *(const float4v*)(xr_ + kk * 32);                          \
        XP[kk][1] = *(const float4v*)(xr_ + kk * 32 + 4);                      \
      }                                                                        \
    }                                                                          \
    __builtin_amdgcn_sched_barrier(0); /* pin load-issue above the shadow work */ \
    /* ---- shadow: xp[t_+1] from XU (K-split + LDS reduce + barrier) ---- */  \
    float4v xacc[4];                                                           \
    _Pragma("unroll")                                                          \
    for (int tile = 0; tile < 4; ++tile) xacc[tile] = (float4v){0.f,0.f,0.f,0.f};\
    _Pragma("unroll")                                                          \
    for (int kk = 0; kk < 4; ++kk) {                                           \
      half8 a;                                                                 \
      _Pragma("unroll")                                                        \
      for (int j = 0; j < 4; ++j) {                                            \
        a[j] = (_Float16)XU[kk][0][j];                                         \
        a[j + 4] = (_Float16)XU[kk][1][j];                                     \
      }                                                                        \
      _Pragma("unroll")                                                        \
      for (int tile = 0; tile < 4; ++tile)                                     \
        xacc[tile] = __builtin_amdgcn_mfma_f32_16x16x32_f16(wih_f[kk][tile], a, xacc[tile], 0, 0, 0); \
    }                                                                          \
    _Pragma("unroll")                                                          \
    for (int tile = 0; tile < 4; ++tile)                                       \
      *(float4v*)&red[PAR][wave][m][tile * 16 + quad * 4] = xacc[tile];        \
    LDSBAR(); /* only barrier per step — in the h-wait shadow */               \
    float4v xp_next = bias4;                                                   \
    _Pragma("unroll")                                                          \
    for (int w = 0; w < 4; ++w) {                                              \
      const float4v v = *(const float4v*)&red[PAR][w][m][wave * 16 + quad * 4];\
      xp_next[0] += v[0]; xp_next[1] += v[1];                                  \
      xp_next[2] += v[2]; xp_next[3] += v[3];                                  \
    }                                                                          \
    /* ---- recurrence: validate h_t, 16 MFMA, tanh, publish ---- */           \
    float4v hacc[4];                                                           \
    _Pragma("unroll")                                                          \
    for (int c = 0; c < 4; ++c) hacc[c] = (float4v){0.f,0.f,0.f,0.f};          \
    if (t_ > 0) {                                                              \
      for (;;) {                                                               \
        bool ok = true;                                                        \
        _Pragma("unroll")                                                      \
        for (int i = 0; i < 32; ++i) ok &= (hw[i] != SENT);                    \
        if (__all((int)ok)) break;                                             \
        __builtin_amdgcn_s_sleep(1);                                           \
        _Pragma("unroll")                                                      \
        for (int i = 0; i < 32; ++i)                                           \
          hw[i] = AL(hbase + (i >> 1) * 8 + quad * 2 + (i & 1));               \
      }                                                                        \
      _Pragma("unroll")                                                        \
      for (int kk = 0; kk < 16; ++kk) {                                        \
        union { u64 u[2]; half8 h; } cv;                                       \
        cv.u[0] = hw[2 * kk]; cv.u[1] = hw[2 * kk + 1];                        \
        hacc[kk & 3] = __builtin_amdgcn_mfma_f32_16x16x32_f16(whh_f[kk], cv.h, hacc[kk & 3], 0, 0, 0); \
      }                                                                        \
    }                                                                          \
    float4v s = xp_cur;                                                        \
    _Pragma("unroll")                                                          \
    for (int c = 0; c < 4; ++c) {                                              \
      s[0] += hacc[c][0]; s[1] += hacc[c][1];                                  \
      s[2] += hacc[c][2]; s[3] += hacc[c][3];                                  \
    }                                                                          \
    float4v o;                                                                 \
    _Pragma("unroll")                                                          \
    for (int j = 0; j < 4; ++j) o[j] = fast_tanh(s[j]);                        \
    if (t_ < TSTEPS - 1) {                                                     \
      u64* dst = (u64*)(hbuf + (size_t)((t_ + 1) & 3) * NB * NH +              \
                        (size_t)myrow * NH + pubcol);                          \
      union { _Float16 h[4]; u64 u; } pk;                                      \
      _Pragma("unroll")                                                        \
      for (int j = 0; j < 4; ++j) pk.h[j] = (_Float16)o[j];                    \
      /* ABA guard: clear (issued at step top) must commit before publish */   \
      asm volatile("s_waitcnt vmcnt(0)" ::: "memory");                         \
      AS(dst, pk.u);                                                           \
    } else {                                                                   \
      *(float4v*)(out + (size_t)myrow * NH + pubcol) = o;                      \
    }                                                                          \
    xp_cur = xp_next;                                                          \
  }

  for (int t = 0; t < TSTEPS; t += 2) {
    STEP(t,     1, xvA, xvB);
    STEP(t + 1, 0, xvB, xvA);
  }
#undef STEP
}

extern "C" void kernel_launch(void* const* d_in, const int* in_sizes, int n_in,
                              void* d_out, int out_size, void* d_ws, size_t ws_size,
                              hipStream_t stream) {
  const float* x   = (const float*)d_in[0];
  const float* Wih = (const float*)d_in[1];
  const float* Whh = (const float*)d_in[2];
  const float* bih = (const float*)d_in[3];
  const float* bhh = (const float*)d_in[4];
  // d_in[5] = hidden_size scalar (unused; H fixed at 512)
  float* out = (float*)d_out;

  _Float16* hbuf = (_Float16*)d_ws;       // ring: 4 x [B][H] fp16 = 2 MB

  // Pre-fill the ring with the sentinel (0xFFFF = fp16 NaN) each launch.
  (void)hipMemsetAsync(hbuf, 0xFF, (size_t)4 * NB * NH * sizeof(_Float16), stream);

  rnn_persistent<<<dim3(256), dim3(256), 0, stream>>>(
      x, Wih, Whh, bih, bhh, out, hbuf);
}